// Round 4
// baseline (224.456 us; speedup 1.0000x reference)
//
#include <hip/hip_runtime.h>

// EdgeModel: out = leaky_relu(concat(x_s[src], x_t[tgt], edge_attr, u[batch]) @ W1 + b1) @ W2 + b2
// F_XS=10, F_XT=5, F_E=10, F_U=10 -> concat 35, hidden 10, out 10.
//
// Round 9: occupancy + barrier-count pass on the round-8 LDS-staged structure.
//   R8 result: 63.7us, FETCH 93MB (ideal), WRITE 78MB (ideal), HBM 35%, VALU 27%,
//   occupancy 53%, bank-conflicts 0 -> still latency-structure bound; no pipe >50%.
//   Changes (memory footprint identical):
//   1) __launch_bounds__(256,8): wave cap 24->32/CU (VGPR 28, LDS 13.3KB x8 = 106KB fit).
//   2) 3 barriers -> 2: idx+attr staged under one sync. The pre-store barrier is NOT
//      needed for the out staging itself: each thread's out slot (row_lds[10*tid..+9])
//      is its own attr slot, read only by itself; only the cooperative store needs a sync.
//   3) compute reorder: attr segment (LDS-sourced) accumulates FIRST, so the 5 divergent
//      gather instrs get ~300 extra cycles to complete before first use.
//   Kept: f16 L2-resident gather tables, dense cooperative NT stream loads, staged
//   dense stores, EPT=1 (EPT4 regressed twice: FETCH +60..130%).

#define F_XS 10
#define F_XT 5
#define F_E  10
#define F_U  10
#define F_IN 35
#define BLOCK 256

typedef float vf4 __attribute__((ext_vector_type(4)));
typedef float vf2 __attribute__((ext_vector_type(2)));
typedef int   vi4 __attribute__((ext_vector_type(4)));
typedef _Float16 f16;

// ---------------- table conversion pass (runs every call, ~5 us) ----------------
__global__ __launch_bounds__(256) void convert_tables_kernel(
    const float* __restrict__ xs, const float* __restrict__ xt, const float* __restrict__ uu,
    f16* __restrict__ xs_h, f16* __restrict__ xt_h, f16* __restrict__ u_h,
    int n_xs_elems, int n_u_elems, int n_t_rows)
{
    const int tid = blockIdx.x * blockDim.x + threadIdx.x;
    if (tid < n_xs_elems) {
        xs_h[tid] = (f16)xs[tid];
    } else if (tid < n_xs_elems + n_u_elems) {
        const int i = tid - n_xs_elems;
        u_h[i] = (f16)uu[i];
    } else {
        const int r = tid - n_xs_elems - n_u_elems;
        if (r < n_t_rows) {
            const float* p = xt + (long long)r * F_XT;
            f16* q = xt_h + (long long)r * 6;
            #pragma unroll
            for (int i = 0; i < 5; ++i) q[i] = (f16)p[i];
            q[5] = (f16)0.f;
        }
    }
}

// ---------------- per-edge math, attr segment FIRST (gathers still in flight) ----------------
__device__ __forceinline__ void compute_edge_attrfirst(
    const f16* __restrict__ s, const f16* __restrict__ t, const f16* __restrict__ uv,
    const float* __restrict__ a,
    const float* __restrict__ W1, const float* __restrict__ b1,
    const float* __restrict__ W2, const float* __restrict__ b2,
    float* __restrict__ o)
{
    float h[F_E];
    #pragma unroll
    for (int j = 0; j < F_E; ++j) h[j] = b1[j];

    #pragma unroll
    for (int k = 0; k < 10; ++k) {          // edge_attr segment, rows 15..24 (LDS, no global dep)
        const float x = a[k];
        #pragma unroll
        for (int j = 0; j < F_E; ++j) h[j] = fmaf(x, W1[(15 + k) * F_E + j], h[j]);
    }
    #pragma unroll
    for (int k = 0; k < 10; ++k) {          // x_s segment, rows 0..9
        const float x = (float)s[k];
        #pragma unroll
        for (int j = 0; j < F_E; ++j) h[j] = fmaf(x, W1[k * F_E + j], h[j]);
    }
    #pragma unroll
    for (int k = 0; k < 5; ++k) {           // x_t segment, rows 10..14
        const float x = (float)t[k];
        #pragma unroll
        for (int j = 0; j < F_E; ++j) h[j] = fmaf(x, W1[(10 + k) * F_E + j], h[j]);
    }
    #pragma unroll
    for (int k = 0; k < 10; ++k) {          // u segment, rows 25..34
        const float x = (float)uv[k];
        #pragma unroll
        for (int j = 0; j < F_E; ++j) h[j] = fmaf(x, W1[(25 + k) * F_E + j], h[j]);
    }

    #pragma unroll
    for (int j = 0; j < F_E; ++j) h[j] = (h[j] >= 0.0f) ? h[j] : 0.1f * h[j];

    #pragma unroll
    for (int j = 0; j < F_E; ++j) o[j] = b2[j];
    #pragma unroll
    for (int k = 0; k < F_E; ++k) {
        const float x = h[k];
        #pragma unroll
        for (int j = 0; j < F_E; ++j) o[j] = fmaf(x, W2[k * F_E + j], o[j]);
    }
}

// ---------------- main kernel: LDS-staged streams, 2 barriers, 8 blocks/CU ----------------
__global__ __launch_bounds__(256, 8) void edge_model_lds2_kernel(
    const f16*   __restrict__ xs_h,       // [N_S, 10] f16
    const f16*   __restrict__ xt_h,       // [N_T, 6]  f16 (padded)
    const int*   __restrict__ edge_index, // [2, E]
    const float* __restrict__ edge_attr,  // [E, 10]
    const f16*   __restrict__ u_h,        // [B, 10] f16
    const int*   __restrict__ batch_e,    // [E]
    const float* __restrict__ W1,         // [35, 10]
    const float* __restrict__ b1,         // [10]
    const float* __restrict__ W2,         // [10, 10]
    const float* __restrict__ b2,         // [10]
    float*       __restrict__ out,        // [E, 10]
    int E)
{
    __shared__ __align__(16) int   idx_lds[3 * BLOCK];    // 3072 B: src|tgt|be
    __shared__ __align__(16) float row_lds[10 * BLOCK];   // 10240 B: attr rows, reused for out rows

    const int tid = threadIdx.x;
    const long long blockBase = (long long)blockIdx.x * BLOCK;

    if (blockBase + BLOCK <= E) {
        // ---- issue idx cooperative load (critical chain root) ----
        vi4 idxv;
        if (tid < 192) {
            const int* p;
            if (tid < 64)       p = edge_index + blockBase + 4 * tid;              // src
            else if (tid < 128) p = edge_index + E + blockBase + 4 * (tid - 64);   // tgt (E%4==0)
            else                p = batch_e + blockBase + 4 * (tid - 128);         // be
            idxv = __builtin_nontemporal_load((const vi4*)p);
        }

        // ---- issue dense attr loads (independent) ----
        const vf4* pa = (const vf4*)(edge_attr + blockBase * F_E);   // 640 x4 slots
        vf4 A0 = __builtin_nontemporal_load(pa + tid);
        vf4 A1 = __builtin_nontemporal_load(pa + tid + 256);
        vf4 A2;
        if (tid < 128) A2 = __builtin_nontemporal_load(pa + tid + 512);

        // ---- stage idx + attr under ONE barrier ----
        if (tid < 192) *(vi4*)(idx_lds + 4 * tid) = idxv;
        *(vf4*)(row_lds + 4 * tid)         = A0;
        *(vf4*)(row_lds + 4 * (tid + 256)) = A1;
        if (tid < 128) *(vf4*)(row_lds + 4 * (tid + 512)) = A2;
        __syncthreads();

        const int src = idx_lds[tid];
        const int tgt = idx_lds[256 + tid];
        const int be  = idx_lds[512 + tid];

        // ---- issue divergent gathers IMMEDIATELY (latency hides under attr reads + attr FMAs) ----
        f16 s[10];  __builtin_memcpy(s,  xs_h + (long long)src * 10, 20);
        f16 tt[8];  __builtin_memcpy(tt, xt_h + (long long)tgt * 6, 16);
        f16 uv[10]; __builtin_memcpy(uv, u_h  + (long long)be  * 10, 20);

        // ---- own attr row from LDS: 5x ds_read_b64, stride 10 words ----
        float af[F_E];
        #pragma unroll
        for (int q = 0; q < 5; ++q) {
            const vf2 v = *(const vf2*)(row_lds + 10 * tid + 2 * q);
            af[2 * q]     = v.x;
            af[2 * q + 1] = v.y;
        }

        // ---- MLP, attr segment first ----
        float o[F_E];
        compute_edge_attrfirst(s, tt, uv, af, W1, b1, W2, b2, o);

        // ---- own out row -> own LDS slot (only this thread ever touches it: no barrier needed) ----
        #pragma unroll
        for (int q = 0; q < 5; ++q) {
            vf2 v; v.x = o[2 * q]; v.y = o[2 * q + 1];
            *(vf2*)(row_lds + 10 * tid + 2 * q) = v;
        }
        __syncthreads();

        // ---- cooperative dense stores: full 64B lines per instruction ----
        float* po = out + blockBase * F_E;
        *(vf4*)(po + 4 * tid)         = *(const vf4*)(row_lds + 4 * tid);
        *(vf4*)(po + 4 * (tid + 256)) = *(const vf4*)(row_lds + 4 * (tid + 256));
        if (tid < 128)
            *(vf4*)(po + 4 * (tid + 512)) = *(const vf4*)(row_lds + 4 * (tid + 512));
    } else {
        // ---- tail block (block-uniform branch; no barriers) ----
        const long long e = blockBase + tid;
        if (e < E) {
            const int src = edge_index[e];
            const int tgt = edge_index[E + e];
            const int be  = batch_e[e];
            f16 s1[10], t1[8], u1[10];
            __builtin_memcpy(s1, xs_h + (long long)src * 10, 20);
            __builtin_memcpy(t1, xt_h + (long long)tgt * 6, 16);
            __builtin_memcpy(u1, u_h  + (long long)be  * 10, 20);
            float a1[F_E];
            #pragma unroll
            for (int k = 0; k < F_E; ++k) a1[k] = edge_attr[e * F_E + k];
            float o1[F_E];
            compute_edge_attrfirst(s1, t1, u1, a1, W1, b1, W2, b2, o1);
            #pragma unroll
            for (int j = 0; j < F_E; ++j) out[e * F_E + j] = o1[j];
        }
    }
}

// ---------------- round-5 single-edge kernel (fallback for E % 4 != 0) ----------------
__global__ __launch_bounds__(256) void edge_model_f16tab_kernel(
    const f16*   __restrict__ xs_h, const f16* __restrict__ xt_h,
    const int*   __restrict__ edge_index, const float* __restrict__ edge_attr,
    const f16*   __restrict__ u_h, const int* __restrict__ batch_e,
    const float* __restrict__ W1, const float* __restrict__ b1,
    const float* __restrict__ W2, const float* __restrict__ b2,
    float* __restrict__ out, int E)
{
    const int e = blockIdx.x * blockDim.x + threadIdx.x;
    if (e >= E) return;

    const int src = __builtin_nontemporal_load(edge_index + e);
    const int tgt = __builtin_nontemporal_load(edge_index + E + e);
    const int be  = __builtin_nontemporal_load(batch_e + e);

    f16 s[10];  __builtin_memcpy(s, xs_h + (long long)src * 10, 20);
    f16 t[8];   __builtin_memcpy(t, xt_h + (long long)tgt * 6, 16);
    f16 uv[10]; __builtin_memcpy(uv, u_h + (long long)be * 10, 20);

    const float* pe = edge_attr + (long long)e * F_E;
    vf4 a0 = __builtin_nontemporal_load((const vf4*)(pe));
    vf4 a1 = __builtin_nontemporal_load((const vf4*)(pe + 4));
    vf2 a2 = __builtin_nontemporal_load((const vf2*)(pe + 8));
    float af[F_E] = {a0.x,a0.y,a0.z,a0.w, a1.x,a1.y,a1.z,a1.w, a2.x,a2.y};

    float o[F_E];
    compute_edge_attrfirst(s, t, uv, af, W1, b1, W2, b2, o);

    float* po = out + (long long)e * F_E;
    vf4 w0; w0.x=o[0]; w0.y=o[1]; w0.z=o[2]; w0.w=o[3];
    vf4 w1; w1.x=o[4]; w1.y=o[5]; w1.z=o[6]; w1.w=o[7];
    vf2 w2; w2.x=o[8]; w2.y=o[9];
    *(vf4*)(po)     = w0;
    *(vf4*)(po + 4) = w1;
    *(vf2*)(po + 8) = w2;
}

// ---------------- fallback: f32 path (if ws too small) ----------------
__global__ __launch_bounds__(256) void edge_model_f32_kernel(
    const float* __restrict__ x_s, const float* __restrict__ x_t,
    const int*   __restrict__ edge_index, const float* __restrict__ edge_attr,
    const float* __restrict__ u, const int* __restrict__ batch_e,
    const float* __restrict__ W1, const float* __restrict__ b1,
    const float* __restrict__ W2, const float* __restrict__ b2,
    float* __restrict__ out, int E)
{
    const int e = blockIdx.x * blockDim.x + threadIdx.x;
    if (e >= E) return;
    const int src = __builtin_nontemporal_load(edge_index + e);
    const int tgt = __builtin_nontemporal_load(edge_index + E + e);
    const int be  = __builtin_nontemporal_load(batch_e + e);

    float in[F_IN];
    __builtin_memcpy(in,      x_s + (long long)src * F_XS, 40);
    __builtin_memcpy(in + 10, x_t + (long long)tgt * F_XT, 20);
    const float* pe = edge_attr + (long long)e * F_E;
    vf4 a0 = __builtin_nontemporal_load((const vf4*)(pe));
    vf4 a1 = __builtin_nontemporal_load((const vf4*)(pe + 4));
    vf2 a2 = __builtin_nontemporal_load((const vf2*)(pe + 8));
    in[15]=a0.x; in[16]=a0.y; in[17]=a0.z; in[18]=a0.w;
    in[19]=a1.x; in[20]=a1.y; in[21]=a1.z; in[22]=a1.w;
    in[23]=a2.x; in[24]=a2.y;
    __builtin_memcpy(in + 25, u + (long long)be * F_U, 40);

    float h[F_E];
    #pragma unroll
    for (int j = 0; j < F_E; ++j) h[j] = b1[j];
    #pragma unroll
    for (int k = 0; k < F_IN; ++k) {
        const float a = in[k];
        #pragma unroll
        for (int j = 0; j < F_E; ++j) h[j] = fmaf(a, W1[k * F_E + j], h[j]);
    }
    #pragma unroll
    for (int j = 0; j < F_E; ++j) h[j] = (h[j] >= 0.0f) ? h[j] : 0.1f * h[j];

    float o[F_E];
    #pragma unroll
    for (int j = 0; j < F_E; ++j) o[j] = b2[j];
    #pragma unroll
    for (int k = 0; k < F_E; ++k) {
        const float a = h[k];
        #pragma unroll
        for (int j = 0; j < F_E; ++j) o[j] = fmaf(a, W2[k * F_E + j], o[j]);
    }
    float* po = out + (long long)e * F_E;
    vf4 w0; w0.x=o[0]; w0.y=o[1]; w0.z=o[2]; w0.w=o[3];
    vf4 w1; w1.x=o[4]; w1.y=o[5]; w1.z=o[6]; w1.w=o[7];
    vf2 w2; w2.x=o[8]; w2.y=o[9];
    *(vf4*)(po)     = w0;
    *(vf4*)(po + 4) = w1;
    *(vf2*)(po + 8) = w2;
}

extern "C" void kernel_launch(void* const* d_in, const int* in_sizes, int n_in,
                              void* d_out, int out_size, void* d_ws, size_t ws_size,
                              hipStream_t stream) {
    const float* x_s        = (const float*)d_in[0];
    const float* x_t        = (const float*)d_in[1];
    const int*   edge_index = (const int*)  d_in[2];
    const float* edge_attr  = (const float*)d_in[3];
    const float* u          = (const float*)d_in[4];
    const int*   batch_e    = (const int*)  d_in[5];
    const float* W1         = (const float*)d_in[6];
    const float* b1         = (const float*)d_in[7];
    const float* W2         = (const float*)d_in[8];
    const float* b2         = (const float*)d_in[9];
    float*       out        = (float*)d_out;

    const int E   = in_sizes[5];           // batch_e is [E]
    const int N_S = in_sizes[0] / F_XS;
    const int N_T = in_sizes[1] / F_XT;
    const int Bn  = in_sizes[4] / F_U;

    // ws layout (16B-aligned regions): xs_h [N_S*10 f16] | xt_h [N_T*6 f16 + 16B slack] | u_h [Bn*10 f16]
    const size_t xs_bytes = (size_t)N_S * 10 * sizeof(f16);
    const size_t xs_off   = 0;
    const size_t xt_off   = (xs_off + xs_bytes + 15) & ~(size_t)15;
    const size_t xt_bytes = (size_t)N_T * 6 * sizeof(f16) + 16;  // +16: dwordx4 slack on last row
    const size_t u_off    = (xt_off + xt_bytes + 15) & ~(size_t)15;
    const size_t u_bytes  = (size_t)Bn * 10 * sizeof(f16);
    const size_t need     = u_off + u_bytes;

    const int block = BLOCK;

    if (ws_size >= need) {
        f16* xs_h = (f16*)((char*)d_ws + xs_off);
        f16* xt_h = (f16*)((char*)d_ws + xt_off);
        f16* u_h  = (f16*)((char*)d_ws + u_off);

        const int n_xs = N_S * 10, n_u = Bn * 10;
        const int conv_threads = n_xs + n_u + N_T;
        convert_tables_kernel<<<(conv_threads + block - 1) / block, block, 0, stream>>>(
            x_s, x_t, u, xs_h, xt_h, u_h, n_xs, n_u, N_T);

        const int grid_e = (E + block - 1) / block;
        if ((E & 3) == 0) {
            edge_model_lds2_kernel<<<grid_e, block, 0, stream>>>(
                xs_h, xt_h, edge_index, edge_attr, u_h, batch_e, W1, b1, W2, b2, out, E);
        } else {
            edge_model_f16tab_kernel<<<grid_e, block, 0, stream>>>(
                xs_h, xt_h, edge_index, edge_attr, u_h, batch_e, W1, b1, W2, b2, out, E);
        }
    } else {
        const int grid_e = (E + block - 1) / block;
        edge_model_f32_kernel<<<grid_e, block, 0, stream>>>(
            x_s, x_t, edge_index, edge_attr, u, batch_e, W1, b1, W2, b2, out, E);
    }
}

// Round 6
// 215.188 us; speedup vs baseline: 1.0431x; 1.0431x over previous
//
#include <hip/hip_runtime.h>

// EdgeModel: out = leaky_relu(concat(x_s[src], x_t[tgt], edge_attr, u[batch]) @ W1 + b1) @ W2 + b2
// F_XS=10, F_XT=5, F_E=10, F_U=10 -> concat 35, hidden 10, out 10.
//
// Round 11: resubmit of round-10 (bench infra failed twice; no counters returned).
//   Kernel audited for hang/fault mechanisms: no s_barrier anywhere in the main
//   kernel (wave_barrier is a zero-instruction scheduling fence -> no deadlock),
//   all LDS/global vector accesses 16B-aligned, per-wave LDS regions in-bounds,
//   E=2e6 -> E%64==0 so the partial-wave path is unused. Launch/capture code
//   identical to 4 passing rounds. Failure attributed to container acquire.
//
// Round 10 rationale (unchanged):
//   R4 post-mortem: merged __syncthreads drained vmcnt(0) (compiler semantics) ->
//   gathers could not overlap attr staging -> 84us despite 75% occupancy. Every
//   __syncthreads in a HIP kernel drains ALL outstanding loads, so cross-phase
//   overlap and block barriers are mutually exclusive. R3 (63.7us) worked because
//   its first barrier drained only the idx load.
//   Fix: stage per WAVE, not per block. Each wave owns a private LDS region
//   (768B idx + 2560B rows; 13.3KB/block total, same as R3). CDNA waves are
//   lockstep and per-wave DS ops execute in program order -> cross-lane LDS RAW
//   inside one wave needs only the compiler's automatic lgkmcnt waits (pinned
//   with free wave_barrier() scheduling fences). ZERO s_barrier -> zero vmcnt(0)
//   drains -> idx, attr and the 5 divergent gathers stay in flight across the
//   whole body.
//   Kept: f16 L2-resident tables, dense coop NT stream loads, dense coop stores,
//   attr-first compute, EPT=1. No launch_bounds min-arg (R4: forcing it strangled
//   the allocator to 20 VGPRs and serialized the gathers).

#define F_XS 10
#define F_XT 5
#define F_E  10
#define F_U  10
#define F_IN 35
#define BLOCK 256
#define WAVES 4

typedef float vf4 __attribute__((ext_vector_type(4)));
typedef float vf2 __attribute__((ext_vector_type(2)));
typedef int   vi4 __attribute__((ext_vector_type(4)));
typedef _Float16 f16;

// ---------------- table conversion pass (runs every call, ~5 us) ----------------
__global__ __launch_bounds__(256) void convert_tables_kernel(
    const float* __restrict__ xs, const float* __restrict__ xt, const float* __restrict__ uu,
    f16* __restrict__ xs_h, f16* __restrict__ xt_h, f16* __restrict__ u_h,
    int n_xs_elems, int n_u_elems, int n_t_rows)
{
    const int tid = blockIdx.x * blockDim.x + threadIdx.x;
    if (tid < n_xs_elems) {
        xs_h[tid] = (f16)xs[tid];
    } else if (tid < n_xs_elems + n_u_elems) {
        const int i = tid - n_xs_elems;
        u_h[i] = (f16)uu[i];
    } else {
        const int r = tid - n_xs_elems - n_u_elems;
        if (r < n_t_rows) {
            const float* p = xt + (long long)r * F_XT;
            f16* q = xt_h + (long long)r * 6;
            #pragma unroll
            for (int i = 0; i < 5; ++i) q[i] = (f16)p[i];
            q[5] = (f16)0.f;
        }
    }
}

// ---------------- per-edge math, attr segment FIRST (gathers still in flight) ----------------
__device__ __forceinline__ void compute_edge_attrfirst(
    const f16* __restrict__ s, const f16* __restrict__ t, const f16* __restrict__ uv,
    const float* __restrict__ a,
    const float* __restrict__ W1, const float* __restrict__ b1,
    const float* __restrict__ W2, const float* __restrict__ b2,
    float* __restrict__ o)
{
    float h[F_E];
    #pragma unroll
    for (int j = 0; j < F_E; ++j) h[j] = b1[j];

    #pragma unroll
    for (int k = 0; k < 10; ++k) {          // edge_attr segment, rows 15..24 (LDS-sourced)
        const float x = a[k];
        #pragma unroll
        for (int j = 0; j < F_E; ++j) h[j] = fmaf(x, W1[(15 + k) * F_E + j], h[j]);
    }
    #pragma unroll
    for (int k = 0; k < 10; ++k) {          // x_s segment, rows 0..9
        const float x = (float)s[k];
        #pragma unroll
        for (int j = 0; j < F_E; ++j) h[j] = fmaf(x, W1[k * F_E + j], h[j]);
    }
    #pragma unroll
    for (int k = 0; k < 5; ++k) {           // x_t segment, rows 10..14
        const float x = (float)t[k];
        #pragma unroll
        for (int j = 0; j < F_E; ++j) h[j] = fmaf(x, W1[(10 + k) * F_E + j], h[j]);
    }
    #pragma unroll
    for (int k = 0; k < 10; ++k) {          // u segment, rows 25..34
        const float x = (float)uv[k];
        #pragma unroll
        for (int j = 0; j < F_E; ++j) h[j] = fmaf(x, W1[(25 + k) * F_E + j], h[j]);
    }

    #pragma unroll
    for (int j = 0; j < F_E; ++j) h[j] = (h[j] >= 0.0f) ? h[j] : 0.1f * h[j];

    #pragma unroll
    for (int j = 0; j < F_E; ++j) o[j] = b2[j];
    #pragma unroll
    for (int k = 0; k < F_E; ++k) {
        const float x = h[k];
        #pragma unroll
        for (int j = 0; j < F_E; ++j) o[j] = fmaf(x, W2[k * F_E + j], o[j]);
    }
}

// ---------------- main kernel: wave-private LDS staging, NO barriers ----------------
__global__ __launch_bounds__(256) void edge_model_wave_kernel(
    const f16*   __restrict__ xs_h,       // [N_S, 10] f16
    const f16*   __restrict__ xt_h,       // [N_T, 6]  f16 (padded)
    const int*   __restrict__ edge_index, // [2, E]
    const float* __restrict__ edge_attr,  // [E, 10]
    const f16*   __restrict__ u_h,        // [B, 10] f16
    const int*   __restrict__ batch_e,    // [E]
    const float* __restrict__ W1,         // [35, 10]
    const float* __restrict__ b1,         // [10]
    const float* __restrict__ W2,         // [10, 10]
    const float* __restrict__ b2,         // [10]
    float*       __restrict__ out,        // [E, 10]
    int E)
{
    // per-wave private regions: 192 ints (src|tgt|be) + 640 floats (attr rows -> out rows)
    __shared__ __align__(16) int   idxw[WAVES][192];   // 3072 B (768 B/wave, 16B-multiple stride)
    __shared__ __align__(16) float roww[WAVES][640];   // 10240 B (2560 B/wave)

    const int tid  = threadIdx.x;
    const int wid  = tid >> 6;
    const int lane = tid & 63;
    const long long wbase = (long long)blockIdx.x * BLOCK + (long long)wid * 64;
    if (wbase >= E) return;

    int*   iw = idxw[wid];
    float* rw = roww[wid];

    if (wbase + 64 <= E) {
        // ---- issue idx coop loads (lanes 0..47, one NT dwordx4 each) ----
        vi4 idxv;
        if (lane < 48) {
            const int* p;
            if (lane < 16)      p = edge_index + wbase + 4 * lane;              // src
            else if (lane < 32) p = edge_index + E + wbase + 4 * (lane - 16);   // tgt (E%4==0)
            else                p = batch_e + wbase + 4 * (lane - 32);          // be
            idxv = __builtin_nontemporal_load((const vi4*)p);
        }

        // ---- issue dense attr loads (160 x4 slots per wave) ----
        const vf4* pa = (const vf4*)(edge_attr + wbase * F_E);
        vf4 A0 = __builtin_nontemporal_load(pa + lane);
        vf4 A1 = __builtin_nontemporal_load(pa + lane + 64);
        vf4 A2;
        if (lane < 32) A2 = __builtin_nontemporal_load(pa + 128 + lane);

        // ---- stage idx (counted vmcnt: waits idx only, attr stays in flight) ----
        if (lane < 48) *(vi4*)(iw + 4 * lane) = idxv;
        __builtin_amdgcn_wave_barrier();   // free: pins DS program order (no runtime cost)

        const int src = iw[lane];
        const int tgt = iw[64 + lane];
        const int be  = iw[128 + lane];

        // ---- issue divergent gathers NOW; they stay in flight across everything below ----
        f16 s[10];  __builtin_memcpy(s,  xs_h + (long long)src * 10, 20);
        f16 tt[8];  __builtin_memcpy(tt, xt_h + (long long)tgt * 6, 16);
        f16 uv[10]; __builtin_memcpy(uv, u_h  + (long long)be  * 10, 20);

        // ---- stage attr (counted vmcnt: waits attr loads, gathers stay in flight) ----
        *(vf4*)(rw + 4 * lane)        = A0;
        *(vf4*)(rw + 4 * (lane + 64)) = A1;
        if (lane < 32) *(vf4*)(rw + 4 * (128 + lane)) = A2;
        __builtin_amdgcn_wave_barrier();

        // ---- own attr row from wave LDS: 5x ds_read_b64 ----
        float af[F_E];
        #pragma unroll
        for (int q = 0; q < 5; ++q) {
            const vf2 v = *(const vf2*)(rw + 10 * lane + 2 * q);
            af[2 * q]     = v.x;
            af[2 * q + 1] = v.y;
        }

        // ---- MLP: attr segment first; gathers drain under it (counted vmcnt) ----
        float o[F_E];
        compute_edge_attrfirst(s, tt, uv, af, W1, b1, W2, b2, o);

        // ---- own out row -> own slot (only this lane reads/writes it; DS in-order) ----
        #pragma unroll
        for (int q = 0; q < 5; ++q) {
            vf2 v; v.x = o[2 * q]; v.y = o[2 * q + 1];
            *(vf2*)(rw + 10 * lane + 2 * q) = v;
        }
        __builtin_amdgcn_wave_barrier();

        // ---- coop dense stores: full 64B lines, wave-private region ----
        float* po = out + wbase * F_E;
        *(vf4*)(po + 4 * lane)        = *(const vf4*)(rw + 4 * lane);
        *(vf4*)(po + 4 * (lane + 64)) = *(const vf4*)(rw + 4 * (lane + 64));
        if (lane < 32)
            *(vf4*)(po + 4 * (128 + lane)) = *(const vf4*)(rw + 4 * (128 + lane));
    } else {
        // ---- partial wave (only if E % 64 != 0; unused at E=2e6): per-edge path ----
        const long long e = wbase + lane;
        if (e < E) {
            const int src = edge_index[e];
            const int tgt = edge_index[E + e];
            const int be  = batch_e[e];
            f16 s1[10], t1[8], u1[10];
            __builtin_memcpy(s1, xs_h + (long long)src * 10, 20);
            __builtin_memcpy(t1, xt_h + (long long)tgt * 6, 16);
            __builtin_memcpy(u1, u_h  + (long long)be  * 10, 20);
            float a1[F_E];
            #pragma unroll
            for (int k = 0; k < F_E; ++k) a1[k] = edge_attr[e * F_E + k];
            float o1[F_E];
            compute_edge_attrfirst(s1, t1, u1, a1, W1, b1, W2, b2, o1);
            #pragma unroll
            for (int j = 0; j < F_E; ++j) out[e * F_E + j] = o1[j];
        }
    }
}

// ---------------- round-5 single-edge kernel (fallback for E % 4 != 0) ----------------
__global__ __launch_bounds__(256) void edge_model_f16tab_kernel(
    const f16*   __restrict__ xs_h, const f16* __restrict__ xt_h,
    const int*   __restrict__ edge_index, const float* __restrict__ edge_attr,
    const f16*   __restrict__ u_h, const int* __restrict__ batch_e,
    const float* __restrict__ W1, const float* __restrict__ b1,
    const float* __restrict__ W2, const float* __restrict__ b2,
    float* __restrict__ out, int E)
{
    const int e = blockIdx.x * blockDim.x + threadIdx.x;
    if (e >= E) return;

    const int src = __builtin_nontemporal_load(edge_index + e);
    const int tgt = __builtin_nontemporal_load(edge_index + E + e);
    const int be  = __builtin_nontemporal_load(batch_e + e);

    f16 s[10];  __builtin_memcpy(s, xs_h + (long long)src * 10, 20);
    f16 t[8];   __builtin_memcpy(t, xt_h + (long long)tgt * 6, 16);
    f16 uv[10]; __builtin_memcpy(uv, u_h + (long long)be * 10, 20);

    const float* pe = edge_attr + (long long)e * F_E;
    vf4 a0 = __builtin_nontemporal_load((const vf4*)(pe));
    vf4 a1 = __builtin_nontemporal_load((const vf4*)(pe + 4));
    vf2 a2 = __builtin_nontemporal_load((const vf2*)(pe + 8));
    float af[F_E] = {a0.x,a0.y,a0.z,a0.w, a1.x,a1.y,a1.z,a1.w, a2.x,a2.y};

    float o[F_E];
    compute_edge_attrfirst(s, t, uv, af, W1, b1, W2, b2, o);

    float* po = out + (long long)e * F_E;
    vf4 w0; w0.x=o[0]; w0.y=o[1]; w0.z=o[2]; w0.w=o[3];
    vf4 w1; w1.x=o[4]; w1.y=o[5]; w1.z=o[6]; w1.w=o[7];
    vf2 w2; w2.x=o[8]; w2.y=o[9];
    *(vf4*)(po)     = w0;
    *(vf4*)(po + 4) = w1;
    *(vf2*)(po + 8) = w2;
}

// ---------------- fallback: f32 path (if ws too small) ----------------
__global__ __launch_bounds__(256) void edge_model_f32_kernel(
    const float* __restrict__ x_s, const float* __restrict__ x_t,
    const int*   __restrict__ edge_index, const float* __restrict__ edge_attr,
    const float* __restrict__ u, const int* __restrict__ batch_e,
    const float* __restrict__ W1, const float* __restrict__ b1,
    const float* __restrict__ W2, const float* __restrict__ b2,
    float* __restrict__ out, int E)
{
    const int e = blockIdx.x * blockDim.x + threadIdx.x;
    if (e >= E) return;
    const int src = __builtin_nontemporal_load(edge_index + e);
    const int tgt = __builtin_nontemporal_load(edge_index + E + e);
    const int be  = __builtin_nontemporal_load(batch_e + e);

    float in[F_IN];
    __builtin_memcpy(in,      x_s + (long long)src * F_XS, 40);
    __builtin_memcpy(in + 10, x_t + (long long)tgt * F_XT, 20);
    const float* pe = edge_attr + (long long)e * F_E;
    vf4 a0 = __builtin_nontemporal_load((const vf4*)(pe));
    vf4 a1 = __builtin_nontemporal_load((const vf4*)(pe + 4));
    vf2 a2 = __builtin_nontemporal_load((const vf2*)(pe + 8));
    in[15]=a0.x; in[16]=a0.y; in[17]=a0.z; in[18]=a0.w;
    in[19]=a1.x; in[20]=a1.y; in[21]=a1.z; in[22]=a1.w;
    in[23]=a2.x; in[24]=a2.y;
    __builtin_memcpy(in + 25, u + (long long)be * F_U, 40);

    float h[F_E];
    #pragma unroll
    for (int j = 0; j < F_E; ++j) h[j] = b1[j];
    #pragma unroll
    for (int k = 0; k < F_IN; ++k) {
        const float a = in[k];
        #pragma unroll
        for (int j = 0; j < F_E; ++j) h[j] = fmaf(a, W1[k * F_E + j], h[j]);
    }
    #pragma unroll
    for (int j = 0; j < F_E; ++j) h[j] = (h[j] >= 0.0f) ? h[j] : 0.1f * h[j];

    float o[F_E];
    #pragma unroll
    for (int j = 0; j < F_E; ++j) o[j] = b2[j];
    #pragma unroll
    for (int k = 0; k < F_E; ++k) {
        const float a = h[k];
        #pragma unroll
        for (int j = 0; j < F_E; ++j) o[j] = fmaf(a, W2[k * F_E + j], o[j]);
    }
    float* po = out + (long long)e * F_E;
    vf4 w0; w0.x=o[0]; w0.y=o[1]; w0.z=o[2]; w0.w=o[3];
    vf4 w1; w1.x=o[4]; w1.y=o[5]; w1.z=o[6]; w1.w=o[7];
    vf2 w2; w2.x=o[8]; w2.y=o[9];
    *(vf4*)(po)     = w0;
    *(vf4*)(po + 4) = w1;
    *(vf2*)(po + 8) = w2;
}

extern "C" void kernel_launch(void* const* d_in, const int* in_sizes, int n_in,
                              void* d_out, int out_size, void* d_ws, size_t ws_size,
                              hipStream_t stream) {
    const float* x_s        = (const float*)d_in[0];
    const float* x_t        = (const float*)d_in[1];
    const int*   edge_index = (const int*)  d_in[2];
    const float* edge_attr  = (const float*)d_in[3];
    const float* u          = (const float*)d_in[4];
    const int*   batch_e    = (const int*)  d_in[5];
    const float* W1         = (const float*)d_in[6];
    const float* b1         = (const float*)d_in[7];
    const float* W2         = (const float*)d_in[8];
    const float* b2         = (const float*)d_in[9];
    float*       out        = (float*)d_out;

    const int E   = in_sizes[5];           // batch_e is [E]
    const int N_S = in_sizes[0] / F_XS;
    const int N_T = in_sizes[1] / F_XT;
    const int Bn  = in_sizes[4] / F_U;

    // ws layout (16B-aligned regions): xs_h [N_S*10 f16] | xt_h [N_T*6 f16 + 16B slack] | u_h [Bn*10 f16]
    const size_t xs_bytes = (size_t)N_S * 10 * sizeof(f16);
    const size_t xs_off   = 0;
    const size_t xt_off   = (xs_off + xs_bytes + 15) & ~(size_t)15;
    const size_t xt_bytes = (size_t)N_T * 6 * sizeof(f16) + 16;  // +16: dwordx4 slack on last row
    const size_t u_off    = (xt_off + xt_bytes + 15) & ~(size_t)15;
    const size_t u_bytes  = (size_t)Bn * 10 * sizeof(f16);
    const size_t need     = u_off + u_bytes;

    const int block = BLOCK;

    if (ws_size >= need) {
        f16* xs_h = (f16*)((char*)d_ws + xs_off);
        f16* xt_h = (f16*)((char*)d_ws + xt_off);
        f16* u_h  = (f16*)((char*)d_ws + u_off);

        const int n_xs = N_S * 10, n_u = Bn * 10;
        const int conv_threads = n_xs + n_u + N_T;
        convert_tables_kernel<<<(conv_threads + block - 1) / block, block, 0, stream>>>(
            x_s, x_t, u, xs_h, xt_h, u_h, n_xs, n_u, N_T);

        const int grid_e = (E + block - 1) / block;
        if ((E & 3) == 0) {
            edge_model_wave_kernel<<<grid_e, block, 0, stream>>>(
                xs_h, xt_h, edge_index, edge_attr, u_h, batch_e, W1, b1, W2, b2, out, E);
        } else {
            edge_model_f16tab_kernel<<<grid_e, block, 0, stream>>>(
                xs_h, xt_h, edge_index, edge_attr, u_h, batch_e, W1, b1, W2, b2, out, E);
        }
    } else {
        const int grid_e = (E + block - 1) / block;
        edge_model_f32_kernel<<<grid_e, block, 0, stream>>>(
            x_s, x_t, edge_index, edge_attr, u, batch_e, W1, b1, W2, b2, out, E);
    }
}

// Round 7
// 209.691 us; speedup vs baseline: 1.0704x; 1.0262x over previous
//
#include <hip/hip_runtime.h>

// EdgeModel: out = leaky_relu(concat(x_s[src], x_t[tgt], edge_attr, u[batch]) @ W1 + b1) @ W2 + b2
// F_XS=10, F_XT=5, F_E=10, F_U=10 -> concat 35, hidden 10, out 10.
//
// Round 12: R3 (best, 63.7us) with NT hints REMOVED — L3-residency play.
//   Cross-round invariant: VALUBusy*dur ~= 17us in every variant -> math constant,
//   stalls vary. R6 (barrier-free) lost to R3 -> barrier drain was NOT the binder.
//   New theory: NT loads force compulsory HBM misses (~900cy) every launch even
//   though the harness replays identical buffers; per-CU BW = inflight/latency
//   caps at ~2.5 TB/s (the cross-session "pinned" number). Full working set
//   (attr 80 + idx 16 + be 8 + out 80 + tables 3.4 + f32 inputs 7 = 194 MB) fits
//   the 256 MB L3. Dropping NT -> streams L3-resident across iterations: latency
//   2-3x down, steady-state FETCH ~0, dirty out lines absorbed.
//   SINGLE-VARIABLE CHANGE vs R3: __builtin_nontemporal_load -> plain loads.
//   Everything else identical (3-barrier LDS staging, launch_bounds(256,6),
//   dense coop loads/stores, f16 L2-resident tables, EPT=1).

#define F_XS 10
#define F_XT 5
#define F_E  10
#define F_U  10
#define F_IN 35
#define BLOCK 256

typedef float vf4 __attribute__((ext_vector_type(4)));
typedef float vf2 __attribute__((ext_vector_type(2)));
typedef int   vi4 __attribute__((ext_vector_type(4)));
typedef _Float16 f16;

// ---------------- table conversion pass (runs every call, ~5 us) ----------------
__global__ __launch_bounds__(256) void convert_tables_kernel(
    const float* __restrict__ xs, const float* __restrict__ xt, const float* __restrict__ uu,
    f16* __restrict__ xs_h, f16* __restrict__ xt_h, f16* __restrict__ u_h,
    int n_xs_elems, int n_u_elems, int n_t_rows)
{
    const int tid = blockIdx.x * blockDim.x + threadIdx.x;
    if (tid < n_xs_elems) {
        xs_h[tid] = (f16)xs[tid];
    } else if (tid < n_xs_elems + n_u_elems) {
        const int i = tid - n_xs_elems;
        u_h[i] = (f16)uu[i];
    } else {
        const int r = tid - n_xs_elems - n_u_elems;
        if (r < n_t_rows) {
            const float* p = xt + (long long)r * F_XT;
            f16* q = xt_h + (long long)r * 6;
            #pragma unroll
            for (int i = 0; i < 5; ++i) q[i] = (f16)p[i];
            q[5] = (f16)0.f;
        }
    }
}

// ---------------- shared per-edge math ----------------
__device__ __forceinline__ void compute_edge(
    const f16* __restrict__ s, const f16* __restrict__ t, const f16* __restrict__ uv,
    const float* __restrict__ a,
    const float* __restrict__ W1, const float* __restrict__ b1,
    const float* __restrict__ W2, const float* __restrict__ b2,
    float* __restrict__ o)
{
    float h[F_E];
    #pragma unroll
    for (int j = 0; j < F_E; ++j) h[j] = b1[j];

    #pragma unroll
    for (int k = 0; k < 10; ++k) {          // x_s segment, rows 0..9
        const float x = (float)s[k];
        #pragma unroll
        for (int j = 0; j < F_E; ++j) h[j] = fmaf(x, W1[k * F_E + j], h[j]);
    }
    #pragma unroll
    for (int k = 0; k < 5; ++k) {           // x_t segment, rows 10..14
        const float x = (float)t[k];
        #pragma unroll
        for (int j = 0; j < F_E; ++j) h[j] = fmaf(x, W1[(10 + k) * F_E + j], h[j]);
    }
    #pragma unroll
    for (int k = 0; k < 10; ++k) {          // edge_attr segment, rows 15..24
        const float x = a[k];
        #pragma unroll
        for (int j = 0; j < F_E; ++j) h[j] = fmaf(x, W1[(15 + k) * F_E + j], h[j]);
    }
    #pragma unroll
    for (int k = 0; k < 10; ++k) {          // u segment, rows 25..34
        const float x = (float)uv[k];
        #pragma unroll
        for (int j = 0; j < F_E; ++j) h[j] = fmaf(x, W1[(25 + k) * F_E + j], h[j]);
    }

    #pragma unroll
    for (int j = 0; j < F_E; ++j) h[j] = (h[j] >= 0.0f) ? h[j] : 0.1f * h[j];

    #pragma unroll
    for (int j = 0; j < F_E; ++j) o[j] = b2[j];
    #pragma unroll
    for (int k = 0; k < F_E; ++k) {
        const float x = h[k];
        #pragma unroll
        for (int j = 0; j < F_E; ++j) o[j] = fmaf(x, W2[k * F_E + j], o[j]);
    }
}

// ---------------- main kernel: LDS-staged streams, plain (cacheable) loads ----------------
__global__ __launch_bounds__(256, 6) void edge_model_lds_l3_kernel(
    const f16*   __restrict__ xs_h,       // [N_S, 10] f16
    const f16*   __restrict__ xt_h,       // [N_T, 6]  f16 (padded)
    const int*   __restrict__ edge_index, // [2, E]
    const float* __restrict__ edge_attr,  // [E, 10]
    const f16*   __restrict__ u_h,        // [B, 10] f16
    const int*   __restrict__ batch_e,    // [E]
    const float* __restrict__ W1,         // [35, 10]
    const float* __restrict__ b1,         // [10]
    const float* __restrict__ W2,         // [10, 10]
    const float* __restrict__ b2,         // [10]
    float*       __restrict__ out,        // [E, 10]
    int E)
{
    __shared__ __align__(16) int   idx_lds[3 * BLOCK];    // 3072 B: src|tgt|be
    __shared__ __align__(16) float row_lds[10 * BLOCK];   // 10240 B: attr rows, reused for out rows

    const int tid = threadIdx.x;
    const long long blockBase = (long long)blockIdx.x * BLOCK;

    if (blockBase + BLOCK <= E) {
        // ---- phase A: issue idx cooperative load FIRST (critical chain root) ----
        vi4 idxv;
        if (tid < 192) {
            const int* p;
            if (tid < 64)       p = edge_index + blockBase + 4 * tid;              // src
            else if (tid < 128) p = edge_index + E + blockBase + 4 * (tid - 64);   // tgt (E%4==0)
            else                p = batch_e + blockBase + 4 * (tid - 128);         // be
            idxv = *(const vi4*)p;
        }

        // ---- phase B: issue dense attr loads (independent; stay in flight) ----
        const vf4* pa = (const vf4*)(edge_attr + blockBase * F_E);   // 640 x4 slots
        vf4 A0 = pa[tid];
        vf4 A1 = pa[tid + 256];
        vf4 A2;
        if (tid < 128) A2 = pa[tid + 512];

        // ---- stage idx (waits the idx load; attr stays outstanding) ----
        if (tid < 192) *(vi4*)(idx_lds + 4 * tid) = idxv;
        __syncthreads();

        const int src = idx_lds[tid];
        const int tgt = idx_lds[256 + tid];
        const int be  = idx_lds[512 + tid];

        // ---- issue divergent gathers EARLY (latency hides under staging) ----
        f16 s[10];  __builtin_memcpy(s,  xs_h + (long long)src * 10, 20);
        f16 tt[8];  __builtin_memcpy(tt, xt_h + (long long)tgt * 6, 16);
        f16 uv[10]; __builtin_memcpy(uv, u_h  + (long long)be  * 10, 20);

        // ---- stage attr rows (waits attr regs; gathers stay outstanding) ----
        *(vf4*)(row_lds + 4 * tid)         = A0;
        *(vf4*)(row_lds + 4 * (tid + 256)) = A1;
        if (tid < 128) *(vf4*)(row_lds + 4 * (tid + 512)) = A2;
        __syncthreads();

        // ---- own attr row: 5x ds_read_b64, stride 10 words (2-way alias = free) ----
        float af[F_E];
        #pragma unroll
        for (int q = 0; q < 5; ++q) {
            const vf2 v = *(const vf2*)(row_lds + 10 * tid + 2 * q);
            af[2 * q]     = v.x;
            af[2 * q + 1] = v.y;
        }

        // ---- MLP (gathers drained here via counted vmcnt) ----
        float o[F_E];
        compute_edge(s, tt, uv, af, W1, b1, W2, b2, o);

        // ---- own out row -> LDS (same words this thread just read: safe) ----
        #pragma unroll
        for (int q = 0; q < 5; ++q) {
            vf2 v; v.x = o[2 * q]; v.y = o[2 * q + 1];
            *(vf2*)(row_lds + 10 * tid + 2 * q) = v;
        }
        __syncthreads();

        // ---- cooperative dense stores: full 64B lines per instruction ----
        float* po = out + blockBase * F_E;
        *(vf4*)(po + 4 * tid)         = *(const vf4*)(row_lds + 4 * tid);
        *(vf4*)(po + 4 * (tid + 256)) = *(const vf4*)(row_lds + 4 * (tid + 256));
        if (tid < 128)
            *(vf4*)(po + 4 * (tid + 512)) = *(const vf4*)(row_lds + 4 * (tid + 512));
    } else {
        // ---- tail block (block-uniform branch; no barriers here) ----
        const long long e = blockBase + tid;
        if (e < E) {
            const int src = edge_index[e];
            const int tgt = edge_index[E + e];
            const int be  = batch_e[e];
            f16 s1[10], t1[8], u1[10];
            __builtin_memcpy(s1, xs_h + (long long)src * 10, 20);
            __builtin_memcpy(t1, xt_h + (long long)tgt * 6, 16);
            __builtin_memcpy(u1, u_h  + (long long)be  * 10, 20);
            float a1[F_E];
            #pragma unroll
            for (int k = 0; k < F_E; ++k) a1[k] = edge_attr[e * F_E + k];
            float o1[F_E];
            compute_edge(s1, t1, u1, a1, W1, b1, W2, b2, o1);
            #pragma unroll
            for (int j = 0; j < F_E; ++j) out[e * F_E + j] = o1[j];
        }
    }
}

// ---------------- single-edge kernel (fallback for E % 4 != 0) ----------------
__global__ __launch_bounds__(256) void edge_model_f16tab_kernel(
    const f16*   __restrict__ xs_h, const f16* __restrict__ xt_h,
    const int*   __restrict__ edge_index, const float* __restrict__ edge_attr,
    const f16*   __restrict__ u_h, const int* __restrict__ batch_e,
    const float* __restrict__ W1, const float* __restrict__ b1,
    const float* __restrict__ W2, const float* __restrict__ b2,
    float* __restrict__ out, int E)
{
    const int e = blockIdx.x * blockDim.x + threadIdx.x;
    if (e >= E) return;

    const int src = edge_index[e];
    const int tgt = edge_index[E + e];
    const int be  = batch_e[e];

    f16 s[10];  __builtin_memcpy(s, xs_h + (long long)src * 10, 20);
    f16 t[8];   __builtin_memcpy(t, xt_h + (long long)tgt * 6, 16);
    f16 uv[10]; __builtin_memcpy(uv, u_h + (long long)be * 10, 20);

    const float* pe = edge_attr + (long long)e * F_E;
    vf4 a0 = *(const vf4*)(pe);
    vf4 a1 = *(const vf4*)(pe + 4);
    vf2 a2 = *(const vf2*)(pe + 8);
    float af[F_E] = {a0.x,a0.y,a0.z,a0.w, a1.x,a1.y,a1.z,a1.w, a2.x,a2.y};

    float o[F_E];
    compute_edge(s, t, uv, af, W1, b1, W2, b2, o);

    float* po = out + (long long)e * F_E;
    vf4 w0; w0.x=o[0]; w0.y=o[1]; w0.z=o[2]; w0.w=o[3];
    vf4 w1; w1.x=o[4]; w1.y=o[5]; w1.z=o[6]; w1.w=o[7];
    vf2 w2; w2.x=o[8]; w2.y=o[9];
    *(vf4*)(po)     = w0;
    *(vf4*)(po + 4) = w1;
    *(vf2*)(po + 8) = w2;
}

// ---------------- fallback: f32 path (if ws too small) ----------------
__global__ __launch_bounds__(256) void edge_model_f32_kernel(
    const float* __restrict__ x_s, const float* __restrict__ x_t,
    const int*   __restrict__ edge_index, const float* __restrict__ edge_attr,
    const float* __restrict__ u, const int* __restrict__ batch_e,
    const float* __restrict__ W1, const float* __restrict__ b1,
    const float* __restrict__ W2, const float* __restrict__ b2,
    float* __restrict__ out, int E)
{
    const int e = blockIdx.x * blockDim.x + threadIdx.x;
    if (e >= E) return;
    const int src = edge_index[e];
    const int tgt = edge_index[E + e];
    const int be  = batch_e[e];

    float in[F_IN];
    __builtin_memcpy(in,      x_s + (long long)src * F_XS, 40);
    __builtin_memcpy(in + 10, x_t + (long long)tgt * F_XT, 20);
    const float* pe = edge_attr + (long long)e * F_E;
    vf4 a0 = *(const vf4*)(pe);
    vf4 a1 = *(const vf4*)(pe + 4);
    vf2 a2 = *(const vf2*)(pe + 8);
    in[15]=a0.x; in[16]=a0.y; in[17]=a0.z; in[18]=a0.w;
    in[19]=a1.x; in[20]=a1.y; in[21]=a1.z; in[22]=a1.w;
    in[23]=a2.x; in[24]=a2.y;
    __builtin_memcpy(in + 25, u + (long long)be * F_U, 40);

    float h[F_E];
    #pragma unroll
    for (int j = 0; j < F_E; ++j) h[j] = b1[j];
    #pragma unroll
    for (int k = 0; k < F_IN; ++k) {
        const float a = in[k];
        #pragma unroll
        for (int j = 0; j < F_E; ++j) h[j] = fmaf(a, W1[k * F_E + j], h[j]);
    }
    #pragma unroll
    for (int j = 0; j < F_E; ++j) h[j] = (h[j] >= 0.0f) ? h[j] : 0.1f * h[j];

    float o[F_E];
    #pragma unroll
    for (int j = 0; j < F_E; ++j) o[j] = b2[j];
    #pragma unroll
    for (int k = 0; k < F_E; ++k) {
        const float a = h[k];
        #pragma unroll
        for (int j = 0; j < F_E; ++j) o[j] = fmaf(a, W2[k * F_E + j], o[j]);
    }
    float* po = out + (long long)e * F_E;
    vf4 w0; w0.x=o[0]; w0.y=o[1]; w0.z=o[2]; w0.w=o[3];
    vf4 w1; w1.x=o[4]; w1.y=o[5]; w1.z=o[6]; w1.w=o[7];
    vf2 w2; w2.x=o[8]; w2.y=o[9];
    *(vf4*)(po)     = w0;
    *(vf4*)(po + 4) = w1;
    *(vf2*)(po + 8) = w2;
}

extern "C" void kernel_launch(void* const* d_in, const int* in_sizes, int n_in,
                              void* d_out, int out_size, void* d_ws, size_t ws_size,
                              hipStream_t stream) {
    const float* x_s        = (const float*)d_in[0];
    const float* x_t        = (const float*)d_in[1];
    const int*   edge_index = (const int*)  d_in[2];
    const float* edge_attr  = (const float*)d_in[3];
    const float* u          = (const float*)d_in[4];
    const int*   batch_e    = (const int*)  d_in[5];
    const float* W1         = (const float*)d_in[6];
    const float* b1         = (const float*)d_in[7];
    const float* W2         = (const float*)d_in[8];
    const float* b2         = (const float*)d_in[9];
    float*       out        = (float*)d_out;

    const int E   = in_sizes[5];           // batch_e is [E]
    const int N_S = in_sizes[0] / F_XS;
    const int N_T = in_sizes[1] / F_XT;
    const int Bn  = in_sizes[4] / F_U;

    // ws layout (16B-aligned regions): xs_h [N_S*10 f16] | xt_h [N_T*6 f16 + 16B slack] | u_h [Bn*10 f16]
    const size_t xs_bytes = (size_t)N_S * 10 * sizeof(f16);
    const size_t xs_off   = 0;
    const size_t xt_off   = (xs_off + xs_bytes + 15) & ~(size_t)15;
    const size_t xt_bytes = (size_t)N_T * 6 * sizeof(f16) + 16;  // +16: dwordx4 slack on last row
    const size_t u_off    = (xt_off + xt_bytes + 15) & ~(size_t)15;
    const size_t u_bytes  = (size_t)Bn * 10 * sizeof(f16);
    const size_t need     = u_off + u_bytes;

    const int block = BLOCK;

    if (ws_size >= need) {
        f16* xs_h = (f16*)((char*)d_ws + xs_off);
        f16* xt_h = (f16*)((char*)d_ws + xt_off);
        f16* u_h  = (f16*)((char*)d_ws + u_off);

        const int n_xs = N_S * 10, n_u = Bn * 10;
        const int conv_threads = n_xs + n_u + N_T;
        convert_tables_kernel<<<(conv_threads + block - 1) / block, block, 0, stream>>>(
            x_s, x_t, u, xs_h, xt_h, u_h, n_xs, n_u, N_T);

        const int grid_e = (E + block - 1) / block;
        if ((E & 3) == 0) {
            edge_model_lds_l3_kernel<<<grid_e, block, 0, stream>>>(
                xs_h, xt_h, edge_index, edge_attr, u_h, batch_e, W1, b1, W2, b2, out, E);
        } else {
            edge_model_f16tab_kernel<<<grid_e, block, 0, stream>>>(
                xs_h, xt_h, edge_index, edge_attr, u_h, batch_e, W1, b1, W2, b2, out, E);
        }
    } else {
        const int grid_e = (E + block - 1) / block;
        edge_model_f32_kernel<<<grid_e, block, 0, stream>>>(
            x_s, x_t, edge_index, edge_attr, u, batch_e, W1, b1, W2, b2, out, E);
    }
}